// Round 19
// baseline (159.703 us; speedup 1.0000x reference)
//
#include <hip/hip_runtime.h>
#include <hip/hip_bf16.h>

#define B_ 256
#define S_ 512
#define F_ 256
#define L_ 20

// ws layout (floats):
//   [0,10240)      W_combT [512][20]
//   [10240,10260)  b_comb[20]
//   [10260,10340)  xw_mu[80]
//   [10340,10420)  bsum[80]
//   [16384, +256*256*80) xw0[b][f][80]
#define WS_WCT 0
#define WS_BC  10240
#define WS_XWMU 10260
#define WS_BSUM 10340
#define WS_XW  16384

#define GISSUE4(dst, ptr) asm volatile("global_load_dwordx4 %0, %1, off" \
  : "=v"(dst) : "v"(ptr) : "memory")
#define GWAIT() { asm volatile("s_waitcnt vmcnt(0)" ::: "memory"); \
  __builtin_amdgcn_sched_barrier(0); }
#define MEMFENCE() asm volatile("" ::: "memory")
#define LGKM0() asm volatile("s_waitcnt lgkmcnt(0)" ::: "memory")
#define VM0() asm volatile("s_waitcnt vmcnt(0)" ::: "memory")

#define DOT20(res, W, S, init0, init1) { \
  float _a0 = (init0), _a1 = (init1), _a2 = 0.f, _a3 = 0.f; \
  _a0 = fmaf(W[0].x, S[0], _a0);  _a1 = fmaf(W[0].y, S[1], _a1); \
  _a2 = fmaf(W[0].z, S[2], _a2);  _a3 = fmaf(W[0].w, S[3], _a3); \
  _a0 = fmaf(W[1].x, S[4], _a0);  _a1 = fmaf(W[1].y, S[5], _a1); \
  _a2 = fmaf(W[1].z, S[6], _a2);  _a3 = fmaf(W[1].w, S[7], _a3); \
  _a0 = fmaf(W[2].x, S[8], _a0);  _a1 = fmaf(W[2].y, S[9], _a1); \
  _a2 = fmaf(W[2].z, S[10], _a2); _a3 = fmaf(W[2].w, S[11], _a3); \
  _a0 = fmaf(W[3].x, S[12], _a0); _a1 = fmaf(W[3].y, S[13], _a1); \
  _a2 = fmaf(W[3].z, S[14], _a2); _a3 = fmaf(W[3].w, S[15], _a3); \
  _a0 = fmaf(W[4].x, S[16], _a0); _a1 = fmaf(W[4].y, S[17], _a1); \
  _a2 = fmaf(W[4].z, S[18], _a2); _a3 = fmaf(W[4].w, S[19], _a3); \
  res = (_a0 + _a1) + (_a2 + _a3); }

#define GLOAD_ROW5(W, base) { \
  GISSUE4(W[0], (base) + 0);  GISSUE4(W[1], (base) + 4); \
  GISSUE4(W[2], (base) + 8);  GISSUE4(W[3], (base) + 12); \
  GISSUE4(W[4], (base) + 16); }

// ---------------- kernel 1: prep (W_comb tiles; W_N read exactly once) ----------------
// blocks 0..31: 16 s-columns each, W_up staged in LDS.
// block 32: b_comb + mu/bsum.
__global__ __launch_bounds__(256) void prep_kernel(
    const float* __restrict__ W_N, const float* __restrict__ b_N,
    const float* __restrict__ W_up, const float* __restrict__ b_up,
    const float* __restrict__ mu, const float* __restrict__ Wih0,
    const float* __restrict__ bih0, const float* __restrict__ bhh0,
    float* __restrict__ wsF)
{
  __shared__ __align__(16) float wupL[10240];
  int blk = blockIdx.x;
  int tid = threadIdx.x;
  if (blk == 32) {
    if (tid < 20) {
      float acc = b_up[tid];
      const float* wu = W_up + (size_t)tid * S_;
#pragma unroll 4
      for (int t = 0; t < S_; ++t) acc = fmaf(wu[t], b_N[t], acc);
      wsF[WS_BC + tid] = acc;
    } else if (tid >= 64 && tid < 144) {
      int g = tid - 64;
      float bs = bih0[g] + bhh0[g];
      wsF[WS_BSUM + g] = bs;
      float acc = bs;
#pragma unroll
      for (int l = 0; l < 20; ++l) acc = fmaf(Wih0[g * 20 + l], mu[l], acc);
      wsF[WS_XWMU + g] = acc;
    }
    return;
  }
  {
    const float4* src = (const float4*)W_up;
    float4* dst = (float4*)wupL;
    for (int i = tid; i < 2560; i += 256) dst[i] = src[i];
  }
  __syncthreads();
  int sl = tid & 15;
  int l0 = tid >> 4;               // 0..15
  int s = blk * 16 + sl;
  const float* wn = W_N + s;
  const float* u0 = wupL + (size_t)l0 * 512;
  const float* u1 = wupL + (size_t)((l0 < 4) ? (l0 + 16) : l0) * 512;
  float a0 = 0.f, a1 = 0.f;
#pragma unroll 4
  for (int t = 0; t < 512; ++t) {
    float wv = wn[(size_t)t * 512];
    a0 = fmaf(u0[t], wv, a0);
    a1 = fmaf(u1[t], wv, a1);
  }
  wsF[WS_WCT + s * 20 + l0] = a0;
  if (l0 < 4) wsF[WS_WCT + s * 20 + l0 + 16] = a1;
}

// ---------------- kernel 2: FUSED xw + lstm, 4-chunk pipelined producer ----------------
// 256 blocks x 512 threads (8 waves), 1 block/CU (~123KB LDS):
//   waves 0-3: xw producer, 4 chunks of 64 f: chunk k = fwd rows [32k,32k+32)
//     + rev rows [224-32k,256-32k). Wave = s-quarter; lane owns ONE f.
//     Double-buffered partials/xu; per-chunk: reduce -> project -> vmcnt(0)
//     -> chunkdone[k] atomic.
//   waves 4-7: r8 lock-free producer/consumer LSTM, gated on chunkdone[k]
//     at steps 1(init)/17/49/81.
__device__ __forceinline__ float rlf(float v, int k) {
  return __int_as_float(__builtin_amdgcn_readlane(__float_as_int(v), k));
}
__device__ __forceinline__ float sigm(float x) {
  return __builtin_amdgcn_rcpf(1.f + __expf(-x));
}
__device__ __forceinline__ float tanh_fast(float x) {
  return fmaf(2.f, __builtin_amdgcn_rcpf(1.f + __expf(-2.f * x)), -1.f);
}

#define READ_H(dst, src) { \
  dst[0]=rlf(src,0);  dst[1]=rlf(src,1);  dst[2]=rlf(src,2);  dst[3]=rlf(src,3); \
  dst[4]=rlf(src,4);  dst[5]=rlf(src,5);  dst[6]=rlf(src,6);  dst[7]=rlf(src,7); \
  dst[8]=rlf(src,8);  dst[9]=rlf(src,9);  dst[10]=rlf(src,10); dst[11]=rlf(src,11); \
  dst[12]=rlf(src,12); dst[13]=rlf(src,13); dst[14]=rlf(src,14); dst[15]=rlf(src,15); \
  dst[16]=rlf(src,16); dst[17]=rlf(src,17); dst[18]=rlf(src,18); dst[19]=rlf(src,19); }

#define PSTEP(PA, PB, STEP) { \
  float preA, preB; \
  DOT20(preA, wA, sh1, PA, 0.f); \
  DOT20(preB, wB, sh1, PB, 0.f); \
  PA = prow[rA]; PB = prow[rB]; \
  prow += ((STEP) <= 251) ? pstep : 0; \
  float aA = fmaf(actA, __builtin_amdgcn_rcpf(1.f + __expf(actB * preA)), actC); \
  float aB = sigm(preB); \
  float fv = __shfl(aA, lf); \
  float gv = __shfl(aA, lg); \
  c1 = fmaf(fv, c1, aA * gv); \
  float h1j = aB * tanh_fast(c1); \
  READ_H(sh1, h1j); \
  float xpA, xpB; \
  DOT20(xpA, iA, sh1, bA1c, 0.f); \
  DOT20(xpB, iB, sh1, bB1c, 0.f); \
  xpring[chain][(STEP) & 31][lane] = xpA; \
  xpring[chain][(STEP) & 31][64 + lane] = xpB; }

#define CSTEP(XA, XB) { \
  float preA, preB; \
  DOT20(preA, hA, sh2, XA, 0.f); \
  DOT20(preB, hB, sh2, XB, 0.f); \
  float aA = fmaf(actA, __builtin_amdgcn_rcpf(1.f + __expf(actB * preA)), actC); \
  float aB = sigm(preB); \
  float fv = __shfl(aA, lf); \
  float gv = __shfl(aA, lg); \
  c2 = fmaf(fv, c2, aA * gv); \
  h2j = aB * tanh_fast(c2); \
  READ_H(sh2, h2j); }

#define CHUNKWAIT(c) { \
  while (((volatile int*)chunkdone)[c] < 4) { asm volatile("s_sleep 2"); } \
  MEMFENCE(); }

__global__ __launch_bounds__(512, 1) void xwlstm_kernel(
    const float* __restrict__ x, const float* __restrict__ Wih0,
    const float* __restrict__ wsF, const float* __restrict__ Whh0,
    const float* __restrict__ Wih1, const float* __restrict__ Whh1,
    const float* __restrict__ bih1, const float* __restrict__ bhh1,
    const float* __restrict__ Wv, const float* __restrict__ bv,
    float* __restrict__ xw, float* __restrict__ out)
{
  __shared__ __align__(16) float Wl[10240];          // 40KB W_combT
  __shared__ __align__(16) float Wg[1600];           // 6.25KB Wih0
  __shared__ __align__(16) float partb[2][3][1344];  // 32.25KB [buf][sq-1][64*21]
  __shared__ __align__(16) float xub[2][1344];       // 10.5KB
  __shared__ __align__(16) float xpring[2][32][128]; // 32KB
  __shared__ float bsumL[80];
  __shared__ float bcL[20];
  __shared__ float hb[2][20];
  __shared__ int pcntS[2], ccntS[2];
  __shared__ int chunkdone[4], redcnt[4], xudone[4];

  int b = blockIdx.x;
  int tid = threadIdx.x;
  int wid = tid >> 6;
  int lane = tid & 63;

  if (tid < 4) { chunkdone[tid] = 0; redcnt[tid] = 0; xudone[tid] = 0; }
  if (tid < 2) { pcntS[tid] = 0; ccntS[tid] = 0; }
  if (tid < 256) {
    const float4* srcw = (const float4*)(wsF + WS_WCT);
    float4* dstw = (float4*)Wl;
#pragma unroll
    for (int i = 0; i < 10; ++i) dstw[tid + 256 * i] = srcw[tid + 256 * i];
    const float4* srcg = (const float4*)Wih0;
    float4* dstg = (float4*)Wg;
    dstg[tid] = srcg[tid];
    if (tid < 144) dstg[256 + tid] = srcg[256 + tid];
    if (tid < 80) bsumL[tid] = wsF[WS_BSUM + tid];
    if (tid < 20) bcL[tid] = wsF[WS_BC + tid];
  }
  __syncthreads();

  if (wid < 4) {
    // ================= xw producer waves =================
    int sq = wid;                      // s-quarter
#pragma unroll 1
    for (int k = 0; k < 4; ++k) {
      int buf = k & 1;
      int f = (lane < 32) ? (32 * k + lane) : (224 - 32 * k + (lane - 32));
      const float* xb = x + (size_t)b * S_ * F_ + f;
      int sbase = sq * 128;
      float acc[20];
#pragma unroll
      for (int l = 0; l < 20; ++l) acc[l] = 0.f;
      float c0 = xb[(size_t)(sbase + 0) * F_];
      float c1v = xb[(size_t)(sbase + 1) * F_];
      float c2v = xb[(size_t)(sbase + 2) * F_];
      float c3v = xb[(size_t)(sbase + 3) * F_];
#pragma unroll 1
      for (int sb = 0; sb < 128; sb += 4) {
        int nb = (sb + 4 < 128) ? sb + 4 : 0;
        float n0 = xb[(size_t)(sbase + nb + 0) * F_];
        float n1 = xb[(size_t)(sbase + nb + 1) * F_];
        float n2 = xb[(size_t)(sbase + nb + 2) * F_];
        float n3 = xb[(size_t)(sbase + nb + 3) * F_];
#define XWB(CUR, SS) { \
        const float4* wp = (const float4*)(Wl + (size_t)(SS) * 20); \
        float4 w0 = wp[0], w1 = wp[1], w2 = wp[2], w3 = wp[3], w4 = wp[4]; \
        acc[0] = fmaf(w0.x, CUR, acc[0]);  acc[1] = fmaf(w0.y, CUR, acc[1]); \
        acc[2] = fmaf(w0.z, CUR, acc[2]);  acc[3] = fmaf(w0.w, CUR, acc[3]); \
        acc[4] = fmaf(w1.x, CUR, acc[4]);  acc[5] = fmaf(w1.y, CUR, acc[5]); \
        acc[6] = fmaf(w1.z, CUR, acc[6]);  acc[7] = fmaf(w1.w, CUR, acc[7]); \
        acc[8] = fmaf(w2.x, CUR, acc[8]);  acc[9] = fmaf(w2.y, CUR, acc[9]); \
        acc[10] = fmaf(w2.z, CUR, acc[10]); acc[11] = fmaf(w2.w, CUR, acc[11]); \
        acc[12] = fmaf(w3.x, CUR, acc[12]); acc[13] = fmaf(w3.y, CUR, acc[13]); \
        acc[14] = fmaf(w3.z, CUR, acc[14]); acc[15] = fmaf(w3.w, CUR, acc[15]); \
        acc[16] = fmaf(w4.x, CUR, acc[16]); acc[17] = fmaf(w4.y, CUR, acc[17]); \
        acc[18] = fmaf(w4.z, CUR, acc[18]); acc[19] = fmaf(w4.w, CUR, acc[19]); }
        XWB(c0, sbase + sb + 0); XWB(c1v, sbase + sb + 1);
        XWB(c2v, sbase + sb + 2); XWB(c3v, sbase + sb + 3);
#undef XWB
        c0 = n0; c1v = n1; c2v = n2; c3v = n3;
      }
      if (sq > 0) {
        float* pp = &partb[buf][sq - 1][lane * 21];
#pragma unroll
        for (int l = 0; l < 20; ++l) pp[l] = acc[l];
        LGKM0();
        if (lane == 0) atomicAdd(&redcnt[k], 1);
      } else {
        while (((volatile int*)redcnt)[k] < 3) { asm volatile("s_sleep 1"); }
        MEMFENCE();
        const float* p0 = &partb[buf][0][lane * 21];
        const float* p1 = &partb[buf][1][lane * 21];
        const float* p2 = &partb[buf][2][lane * 21];
        float* xp = &xub[buf][lane * 21];
#pragma unroll
        for (int l = 0; l < 20; ++l)
          xp[l] = acc[l] + p0[l] + p1[l] + p2[l] + bcL[l];
        LGKM0();
        if (lane == 0) ((volatile int*)xudone)[k] = 1;
      }
      while (((volatile int*)xudone)[k] == 0) { asm volatile("s_sleep 1"); }
      MEMFENCE();
      // projection: 256 producer threads; fl = f-slot, gh = gate-group of 20
      int fl = tid & 63, gh = tid >> 6;
      float xr[20];
      const float* xp2 = &xub[buf][fl * 21];
#pragma unroll
      for (int l = 0; l < 20; ++l) xr[l] = xp2[l];
      int fo = (fl < 32) ? (32 * k + fl) : (224 - 32 * k + (fl - 32));
      float* ob = xw + ((size_t)b * 256 + fo) * 80 + gh * 20;
      const float* wgbase = Wg + gh * 20 * 20;
      const float* bsb = bsumL + gh * 20;
#pragma unroll 2
      for (int g = 0; g < 20; ++g) {
        const float4* wp = (const float4*)(wgbase + g * 20);
        float4 w0 = wp[0], w1 = wp[1], w2 = wp[2], w3 = wp[3], w4 = wp[4];
        float a0 = bsb[g], a1 = 0.f, a2 = 0.f, a3 = 0.f;
        a0 = fmaf(w0.x, xr[0], a0);  a1 = fmaf(w0.y, xr[1], a1);
        a2 = fmaf(w0.z, xr[2], a2);  a3 = fmaf(w0.w, xr[3], a3);
        a0 = fmaf(w1.x, xr[4], a0);  a1 = fmaf(w1.y, xr[5], a1);
        a2 = fmaf(w1.z, xr[6], a2);  a3 = fmaf(w1.w, xr[7], a3);
        a0 = fmaf(w2.x, xr[8], a0);  a1 = fmaf(w2.y, xr[9], a1);
        a2 = fmaf(w2.z, xr[10], a2); a3 = fmaf(w2.w, xr[11], a3);
        a0 = fmaf(w3.x, xr[12], a0); a1 = fmaf(w3.y, xr[13], a1);
        a2 = fmaf(w3.z, xr[14], a2); a3 = fmaf(w3.w, xr[15], a3);
        a0 = fmaf(w4.x, xr[16], a0); a1 = fmaf(w4.y, xr[17], a1);
        a2 = fmaf(w4.z, xr[18], a2); a3 = fmaf(w4.w, xr[19], a3);
        ob[g] = (a0 + a1) + (a2 + a3);
      }
      VM0();
      if (lane == 0) atomicAdd(&chunkdone[k], 1);
    }
  } else {
    // ================= lstm waves (r8, validated) =================
    int wid2 = wid - 4;
    int chain = wid2 >> 1;   // 0 = fwd, 1 = rev
    int role = wid2 & 1;     // 0 = producer, 1 = consumer
    int jmod = lane % 20;
    int rA = lane, rB = 60 + jmod;
    int lf = (lane + 20) & 63;
    int lg = (lane + 40) & 63;
    int typ = lane / 20;
    float actB = (typ == 2) ? -2.f : -1.f;
    float actA = (typ == 2) ? 2.f : 1.f;
    float actC = (typ == 2) ? -1.f : 0.f;
    volatile int* pcnt = &pcntS[chain];
    volatile int* ccnt = &ccntS[chain];

    if (role == 0) {
      float4 wA[5], wB[5], iA[5], iB[5];
      GLOAD_ROW5(wA, Whh0 + rA * 20);
      GLOAD_ROW5(wB, Whh0 + rB * 20);
      GLOAD_ROW5(iA, Wih1 + rA * 20);
      GLOAD_ROW5(iB, Wih1 + rB * 20);
      GWAIT();
      float bA1c = bih1[rA] + bhh1[rA];
      float bB1c = bih1[rB] + bhh1[rB];
      CHUNKWAIT(0);                     // rows 0..31 / 224..255 ready
      const float* prow = xw + ((size_t)b * 256 + (chain ? 255 : 0)) * 80;
      int pstep = chain ? -80 : 80;
      float pA0 = prow[rA], pB0 = prow[rB]; prow += pstep;
      float pA1 = prow[rA], pB1 = prow[rB]; prow += pstep;
      float pA2 = prow[rA], pB2 = prow[rB]; prow += pstep;
      float pA3 = prow[rA], pB3 = prow[rB]; prow += pstep;

      float sh1[20];
      float c1;
      {   // step 0: input = mu projection, h=c=0
        float preA = wsF[WS_XWMU + rA];
        float preB = wsF[WS_XWMU + rB];
        float aA = fmaf(actA, __builtin_amdgcn_rcpf(1.f + __expf(actB * preA)), actC);
        float aB = sigm(preB);
        float gv = __shfl(aA, lg);
        c1 = aA * gv;
        float h1j = aB * tanh_fast(c1);
        READ_H(sh1, h1j);
        float xpA, xpB;
        DOT20(xpA, iA, sh1, bA1c, 0.f);
        DOT20(xpB, iB, sh1, bB1c, 0.f);
        xpring[chain][0][lane] = xpA;
        xpring[chain][0][64 + lane] = xpB;
        LGKM0();
        *pcnt = 1;
        MEMFENCE();
      }
#pragma unroll 1
      for (int t = 1; t <= 253; t += 4) {
        if (((t - 1) & 15) == 0) {
          if (t == 17) CHUNKWAIT(1);
          if (t == 49) CHUNKWAIT(2);
          if (t == 81) CHUNKWAIT(3);
          while (*ccnt < t - 13) { }
          MEMFENCE();
        }
        PSTEP(pA0, pB0, t);
        PSTEP(pA1, pB1, t + 1);
        PSTEP(pA2, pB2, t + 2);
        PSTEP(pA3, pB3, t + 3);
        LGKM0();
        *pcnt = t + 4;
        MEMFENCE();
      }
    } else {
      float4 hA[5], hB[5];
      GLOAD_ROW5(hA, Whh1 + rA * 20);
      GLOAD_ROW5(hB, Whh1 + rB * 20);
      GWAIT();
      float sh2[20];
#pragma unroll
      for (int k = 0; k < 20; ++k) sh2[k] = 0.f;
      float c2 = 0.f;
      float h2j = 0.f;
#pragma unroll 1
      for (int t = 0; t <= 252; t += 4) {
        while (*pcnt < t + 4) { }
        MEMFENCE();
        int sl = t & 31;
        float xA0 = xpring[chain][sl][lane],     xB0 = xpring[chain][sl][64 + lane];
        float xA1 = xpring[chain][sl + 1][lane], xB1 = xpring[chain][sl + 1][64 + lane];
        float xA2 = xpring[chain][sl + 2][lane], xB2 = xpring[chain][sl + 2][64 + lane];
        float xA3 = xpring[chain][sl + 3][lane], xB3 = xpring[chain][sl + 3][64 + lane];
        CSTEP(xA0, xB0);
        CSTEP(xA1, xB1);
        CSTEP(xA2, xB2);
        CSTEP(xA3, xB3);
        *ccnt = t + 4;
        MEMFENCE();
      }
      {   // tail step t=256
        while (*pcnt < 257) { }
        MEMFENCE();
        float xA = xpring[chain][256 & 31][lane];
        float xB = xpring[chain][256 & 31][64 + lane];
        CSTEP(xA, xB);
        if (lane < 20) hb[chain][lane] = h2j;
      }
    }
  }

  __syncthreads();
  if (tid == 0) {
    float y = bv[0];
#pragma unroll
    for (int j = 0; j < 20; ++j) y = fmaf(Wv[j], hb[0][j], y);
#pragma unroll
    for (int j = 0; j < 20; ++j) y = fmaf(Wv[20 + j], hb[1][j], y);
    out[b] = y;
  }
}

extern "C" void kernel_launch(void* const* d_in, const int* in_sizes, int n_in,
                              void* d_out, int out_size, void* d_ws, size_t ws_size,
                              hipStream_t stream)
{
  const float* x    = (const float*)d_in[0];
  const float* W_N  = (const float*)d_in[1];
  const float* b_N  = (const float*)d_in[2];
  const float* W_up = (const float*)d_in[3];
  const float* b_up = (const float*)d_in[4];
  const float* mu   = (const float*)d_in[5];
  const float* Wih0 = (const float*)d_in[6];
  const float* Whh0 = (const float*)d_in[7];
  const float* bih0 = (const float*)d_in[8];
  const float* bhh0 = (const float*)d_in[9];
  const float* Wih1 = (const float*)d_in[10];
  const float* Whh1 = (const float*)d_in[11];
  const float* bih1 = (const float*)d_in[12];
  const float* bhh1 = (const float*)d_in[13];
  const float* Wv   = (const float*)d_in[14];
  const float* bvv  = (const float*)d_in[15];
  float* wsF = (float*)d_ws;
  float* xwp = wsF + WS_XW;
  float* outF = (float*)d_out;

  prep_kernel<<<33, 256, 0, stream>>>(W_N, b_N, W_up, b_up,
                                      mu, Wih0, bih0, bhh0, wsF);
  xwlstm_kernel<<<B_, 512, 0, stream>>>(x, Wih0, wsF, Whh0, Wih1, Whh1,
                                        bih1, bhh1, Wv, bvv, xwp, outF);
}

// Round 21
// 121.786 us; speedup vs baseline: 1.3113x; 1.3113x over previous
//
#include <hip/hip_runtime.h>
#include <hip/hip_bf16.h>

#define B_ 256
#define S_ 512
#define F_ 256
#define L_ 20

// ws layout (floats):
//   [0,10240)      W_combT [512][20]
//   [10240,10260)  b_comb[20]
//   [10260,10340)  xw_mu[80]  = bih0+bhh0 + W_ih0·mu
//   [10340,10420)  bsum[80]   = bih0+bhh0
//   [16384, +256*256*80) xw0[b][f][80]
#define WS_WCT 0
#define WS_BC  10240
#define WS_XWMU 10260
#define WS_BSUM 10340
#define WS_XW  16384

// Non-rematerializable weight loads (volatile asm cannot be re-executed).
#define GISSUE4(dst, ptr) asm volatile("global_load_dwordx4 %0, %1, off" \
  : "=v"(dst) : "v"(ptr) : "memory")
#define GWAIT() { asm volatile("s_waitcnt vmcnt(0)" ::: "memory"); \
  __builtin_amdgcn_sched_barrier(0); }
#define MEMFENCE() asm volatile("" ::: "memory")
#define LGKM0() asm volatile("s_waitcnt lgkmcnt(0)" ::: "memory")
#define VM0() asm volatile("s_waitcnt vmcnt(0)" ::: "memory")

// dot of a 5xfloat4 register row with a 20-float array, 4-acc ILP (scalar)
#define DOT20(res, W, S, init0, init1) { \
  float _a0 = (init0), _a1 = (init1), _a2 = 0.f, _a3 = 0.f; \
  _a0 = fmaf(W[0].x, S[0], _a0);  _a1 = fmaf(W[0].y, S[1], _a1); \
  _a2 = fmaf(W[0].z, S[2], _a2);  _a3 = fmaf(W[0].w, S[3], _a3); \
  _a0 = fmaf(W[1].x, S[4], _a0);  _a1 = fmaf(W[1].y, S[5], _a1); \
  _a2 = fmaf(W[1].z, S[6], _a2);  _a3 = fmaf(W[1].w, S[7], _a3); \
  _a0 = fmaf(W[2].x, S[8], _a0);  _a1 = fmaf(W[2].y, S[9], _a1); \
  _a2 = fmaf(W[2].z, S[10], _a2); _a3 = fmaf(W[2].w, S[11], _a3); \
  _a0 = fmaf(W[3].x, S[12], _a0); _a1 = fmaf(W[3].y, S[13], _a1); \
  _a2 = fmaf(W[3].z, S[14], _a2); _a3 = fmaf(W[3].w, S[15], _a3); \
  _a0 = fmaf(W[4].x, S[16], _a0); _a1 = fmaf(W[4].y, S[17], _a1); \
  _a2 = fmaf(W[4].z, S[18], _a2); _a3 = fmaf(W[4].w, S[19], _a3); \
  res = (_a0 + _a1) + (_a2 + _a3); }

#define GLOAD_ROW5(W, base) { \
  GISSUE4(W[0], (base) + 0);  GISSUE4(W[1], (base) + 4); \
  GISSUE4(W[2], (base) + 8);  GISSUE4(W[3], (base) + 12); \
  GISSUE4(W[4], (base) + 16); }

// ---------------- kernel 1: W_combT columns + b_comb + mu/bsum (merged) ----------------
__global__ __launch_bounds__(256) void prep_cols_kernel(
    const float* __restrict__ W_N, const float* __restrict__ b_N,
    const float* __restrict__ W_up, const float* __restrict__ b_up,
    const float* __restrict__ mu, const float* __restrict__ Wih0,
    const float* __restrict__ bih0, const float* __restrict__ bhh0,
    float* __restrict__ wsF)
{
  __shared__ float wn[512];
  int s = blockIdx.x;                 // 0..511: column s; 512: b_comb; 513: mu/bsum
  int tid = threadIdx.x;
  if (s == 513) {
    if (tid < 80) {
      float bs = bih0[tid] + bhh0[tid];
      wsF[WS_BSUM + tid] = bs;
      float acc = bs;
#pragma unroll
      for (int l = 0; l < 20; ++l) acc = fmaf(Wih0[tid * 20 + l], mu[l], acc);
      wsF[WS_XWMU + tid] = acc;
    }
    return;
  }
  bool isb = (s == 512);
  if (isb) {
    wn[tid] = b_N[tid];
    wn[tid + 256] = b_N[tid + 256];
  } else {
    wn[tid] = W_N[(size_t)tid * S_ + s];
    wn[tid + 256] = W_N[(size_t)(tid + 256) * S_ + s];
  }
  __syncthreads();
  int w = tid >> 6, lane = tid & 63;
#pragma unroll
  for (int li = 0; li < 5; ++li) {
    int l = w * 5 + li;
    const float* wu = W_up + (size_t)l * S_;
    float acc = 0.f;
#pragma unroll
    for (int j = 0; j < 8; ++j)
      acc = fmaf(wu[lane + 64 * j], wn[lane + 64 * j], acc);
    acc += __shfl_xor(acc, 1);  acc += __shfl_xor(acc, 2);
    acc += __shfl_xor(acc, 4);  acc += __shfl_xor(acc, 8);
    acc += __shfl_xor(acc, 16); acc += __shfl_xor(acc, 32);
    if (lane == 0) {
      if (isb) wsF[WS_BC + l] = acc + b_up[l];
      else     wsF[WS_WCT + s * 20 + l] = acc;
    }
  }
}

// ---------------- kernel 2: FUSED xw + lstm (r18, validated 122.5us) ----------------
// 256 blocks x 512 threads (8 waves), 1 block/CU (124KB LDS):
//   waves 0-3: xw producer. Two f-chunks: A = {0..63, 192..255} (both chains'
//     first 64 rows), B = {64..191}. Wave = s-quarter; lane covers 2 f
//     (weight rows stay wave-broadcast). Cross-wave s-reduce via LDS; gate
//     projection; global store; vmcnt(0) -> LDS atomic chunkdone flag.
//   waves 4-7: r8 lock-free producer/consumer LSTM (validated), gated on
//     chunkdone[0] at start and chunkdone[1] at step 49.
// All sync intra-block (co-resident by definition -> no dispatch-order hazard).
__device__ __forceinline__ float rlf(float v, int k) {
  return __int_as_float(__builtin_amdgcn_readlane(__float_as_int(v), k));
}
__device__ __forceinline__ float sigm(float x) {
  return __builtin_amdgcn_rcpf(1.f + __expf(-x));
}
__device__ __forceinline__ float tanh_fast(float x) {
  return fmaf(2.f, __builtin_amdgcn_rcpf(1.f + __expf(-2.f * x)), -1.f);
}

#define READ_H(dst, src) { \
  dst[0]=rlf(src,0);  dst[1]=rlf(src,1);  dst[2]=rlf(src,2);  dst[3]=rlf(src,3); \
  dst[4]=rlf(src,4);  dst[5]=rlf(src,5);  dst[6]=rlf(src,6);  dst[7]=rlf(src,7); \
  dst[8]=rlf(src,8);  dst[9]=rlf(src,9);  dst[10]=rlf(src,10); dst[11]=rlf(src,11); \
  dst[12]=rlf(src,12); dst[13]=rlf(src,13); dst[14]=rlf(src,14); dst[15]=rlf(src,15); \
  dst[16]=rlf(src,16); dst[17]=rlf(src,17); dst[18]=rlf(src,18); dst[19]=rlf(src,19); }

#define PSTEP(PA, PB, STEP) { \
  float preA, preB; \
  DOT20(preA, wA, sh1, PA, 0.f); \
  DOT20(preB, wB, sh1, PB, 0.f); \
  PA = prow[rA]; PB = prow[rB]; \
  prow += ((STEP) <= 251) ? pstep : 0; \
  float aA = fmaf(actA, __builtin_amdgcn_rcpf(1.f + __expf(actB * preA)), actC); \
  float aB = sigm(preB); \
  float fv = __shfl(aA, lf); \
  float gv = __shfl(aA, lg); \
  c1 = fmaf(fv, c1, aA * gv); \
  float h1j = aB * tanh_fast(c1); \
  READ_H(sh1, h1j); \
  float xpA, xpB; \
  DOT20(xpA, iA, sh1, bA1c, 0.f); \
  DOT20(xpB, iB, sh1, bB1c, 0.f); \
  xpring[chain][(STEP) & 31][lane] = xpA; \
  xpring[chain][(STEP) & 31][64 + lane] = xpB; }

#define CSTEP(XA, XB) { \
  float preA, preB; \
  DOT20(preA, hA, sh2, XA, 0.f); \
  DOT20(preB, hB, sh2, XB, 0.f); \
  float aA = fmaf(actA, __builtin_amdgcn_rcpf(1.f + __expf(actB * preA)), actC); \
  float aB = sigm(preB); \
  float fv = __shfl(aA, lf); \
  float gv = __shfl(aA, lg); \
  c2 = fmaf(fv, c2, aA * gv); \
  h2j = aB * tanh_fast(c2); \
  READ_H(sh2, h2j); }

#define CHUNKWAIT(c) { \
  while (((volatile int*)chunkdone)[c] < 4) { asm volatile("s_sleep 2"); } \
  MEMFENCE(); }

__global__ __launch_bounds__(512, 1) void xwlstm_kernel(
    const float* __restrict__ x, const float* __restrict__ Wih0,
    const float* __restrict__ wsF, const float* __restrict__ Whh0,
    const float* __restrict__ Wih1, const float* __restrict__ Whh1,
    const float* __restrict__ bih1, const float* __restrict__ bhh1,
    const float* __restrict__ Wv, const float* __restrict__ bv,
    float* __restrict__ xw, float* __restrict__ out)
{
  __shared__ __align__(16) float Wl[10240];       // 40KB W_combT
  __shared__ __align__(16) float Wg[1600];        // 6.25KB Wih0
  __shared__ __align__(16) float partb[8064];     // 31.5KB [3][64][42]
  __shared__ __align__(16) float xub[2688];       // 10.5KB [64][42]
  __shared__ __align__(16) float xpring[2][32][128]; // 32KB
  __shared__ float bsumL[80];
  __shared__ float bcL[20];
  __shared__ float hb[2][20];
  __shared__ int pcntS[2], ccntS[2], chunkdone[2], redcnt[2], xudone[2];

  int b = blockIdx.x;
  int tid = threadIdx.x;
  int wid = tid >> 6;
  int lane = tid & 63;

  if (tid < 2) {
    pcntS[tid] = 0; ccntS[tid] = 0;
    chunkdone[tid] = 0; redcnt[tid] = 0; xudone[tid] = 0;
  }
  if (tid < 256) {
    const float4* srcw = (const float4*)(wsF + WS_WCT);
    float4* dstw = (float4*)Wl;
#pragma unroll
    for (int i = 0; i < 10; ++i) dstw[tid + 256 * i] = srcw[tid + 256 * i];
    const float4* srcg = (const float4*)Wih0;
    float4* dstg = (float4*)Wg;
    dstg[tid] = srcg[tid];
    if (tid < 144) dstg[256 + tid] = srcg[256 + tid];
    if (tid < 80) bsumL[tid] = wsF[WS_BSUM + tid];
    if (tid < 20) bcL[tid] = wsF[WS_BC + tid];
  }
  __syncthreads();

  if (wid < 4) {
    // ================= xw producer waves =================
    int sq = wid;                      // s-quarter
#pragma unroll 1
    for (int ci = 0; ci < 2; ++ci) {
      int f0l = (ci == 0) ? ((lane < 32) ? lane * 2 : 192 + (lane - 32) * 2)
                          : 64 + lane * 2;
      const float* xb = x + (size_t)b * S_ * F_ + f0l;
      int sbase = sq * 128;
      float aA[20], aB[20];
#pragma unroll
      for (int l = 0; l < 20; ++l) { aA[l] = 0.f; aB[l] = 0.f; }
      float2 cc0 = *(const float2*)(xb + (size_t)(sbase + 0) * F_);
      float2 cc1 = *(const float2*)(xb + (size_t)(sbase + 1) * F_);
      float2 cc2 = *(const float2*)(xb + (size_t)(sbase + 2) * F_);
      float2 cc3 = *(const float2*)(xb + (size_t)(sbase + 3) * F_);
#pragma unroll 1
      for (int sb = 0; sb < 128; sb += 4) {
        int nb = (sb + 4 < 128) ? sb + 4 : 0;
        float2 nn0 = *(const float2*)(xb + (size_t)(sbase + nb + 0) * F_);
        float2 nn1 = *(const float2*)(xb + (size_t)(sbase + nb + 1) * F_);
        float2 nn2 = *(const float2*)(xb + (size_t)(sbase + nb + 2) * F_);
        float2 nn3 = *(const float2*)(xb + (size_t)(sbase + nb + 3) * F_);
#define XWB(CUR, SS) { \
        const float4* wp = (const float4*)(Wl + (size_t)(SS) * 20); \
        float4 w0 = wp[0], w1 = wp[1], w2 = wp[2], w3 = wp[3], w4 = wp[4]; \
        float wv[20] = {w0.x,w0.y,w0.z,w0.w, w1.x,w1.y,w1.z,w1.w, \
                        w2.x,w2.y,w2.z,w2.w, w3.x,w3.y,w3.z,w3.w, \
                        w4.x,w4.y,w4.z,w4.w}; \
        _Pragma("unroll") \
        for (int l = 0; l < 20; ++l) { \
          aA[l] = fmaf(wv[l], CUR.x, aA[l]); \
          aB[l] = fmaf(wv[l], CUR.y, aB[l]); \
        } }
        XWB(cc0, sbase + sb + 0); XWB(cc1, sbase + sb + 1);
        XWB(cc2, sbase + sb + 2); XWB(cc3, sbase + sb + 3);
#undef XWB
        cc0 = nn0; cc1 = nn1; cc2 = nn2; cc3 = nn3;
      }
      int slot = lane;
      if (sq > 0) {
        float* pp = partb + (sq - 1) * 2688 + slot * 42;
#pragma unroll
        for (int l = 0; l < 20; ++l) { pp[l] = aA[l]; pp[21 + l] = aB[l]; }
        LGKM0();
        if (lane == 0) atomicAdd(&redcnt[ci], 1);
      } else {
        while (((volatile int*)redcnt)[ci] < 3) { asm volatile("s_sleep 1"); }
        MEMFENCE();
        const float* p0 = partb + slot * 42;
        const float* p1 = partb + 2688 + slot * 42;
        const float* p2 = partb + 5376 + slot * 42;
        float* xp = xub + slot * 42;
#pragma unroll
        for (int l = 0; l < 20; ++l) {
          xp[l]      = aA[l] + p0[l] + p1[l] + p2[l] + bcL[l];
          xp[21 + l] = aB[l] + p0[21 + l] + p1[21 + l] + p2[21 + l] + bcL[l];
        }
        LGKM0();
        if (lane == 0) ((volatile int*)xudone)[ci] = 1;
      }
      while (((volatile int*)xudone)[ci] == 0) { asm volatile("s_sleep 1"); }
      MEMFENCE();
      // projection: 256 threads, fl = tid&127 (f within chunk), gh = tid>>7
      int fl = tid & 127, gh = tid >> 7;
      int slot2 = fl >> 1, sub = fl & 1;
      float xr[20];
      const float* xp2 = xub + slot2 * 42 + sub * 21;
#pragma unroll
      for (int l = 0; l < 20; ++l) xr[l] = xp2[l];
      int f = (ci == 0) ? ((fl < 64) ? fl : 128 + fl) : 64 + fl;
      float* ob = xw + ((size_t)b * 256 + f) * 80 + gh * 40;
      const float* wgbase = Wg + gh * 40 * 20;
      const float* bsb = bsumL + gh * 40;
#pragma unroll 2
      for (int g = 0; g < 40; ++g) {
        const float4* wp = (const float4*)(wgbase + g * 20);
        float4 w0 = wp[0], w1 = wp[1], w2 = wp[2], w3 = wp[3], w4 = wp[4];
        float a0 = bsb[g], a1 = 0.f, a2 = 0.f, a3 = 0.f;
        a0 = fmaf(w0.x, xr[0], a0);  a1 = fmaf(w0.y, xr[1], a1);
        a2 = fmaf(w0.z, xr[2], a2);  a3 = fmaf(w0.w, xr[3], a3);
        a0 = fmaf(w1.x, xr[4], a0);  a1 = fmaf(w1.y, xr[5], a1);
        a2 = fmaf(w1.z, xr[6], a2);  a3 = fmaf(w1.w, xr[7], a3);
        a0 = fmaf(w2.x, xr[8], a0);  a1 = fmaf(w2.y, xr[9], a1);
        a2 = fmaf(w2.z, xr[10], a2); a3 = fmaf(w2.w, xr[11], a3);
        a0 = fmaf(w3.x, xr[12], a0); a1 = fmaf(w3.y, xr[13], a1);
        a2 = fmaf(w3.z, xr[14], a2); a3 = fmaf(w3.w, xr[15], a3);
        a0 = fmaf(w4.x, xr[16], a0); a1 = fmaf(w4.y, xr[17], a1);
        a2 = fmaf(w4.z, xr[18], a2); a3 = fmaf(w4.w, xr[19], a3);
        ob[g] = (a0 + a1) + (a2 + a3);
      }
      VM0();
      if (lane == 0) atomicAdd(&chunkdone[ci], 1);
    }
  } else {
    // ================= lstm waves (r8, validated) =================
    int wid2 = wid - 4;
    int chain = wid2 >> 1;   // 0 = fwd, 1 = rev
    int role = wid2 & 1;     // 0 = producer, 1 = consumer
    int jmod = lane % 20;
    int rA = lane, rB = 60 + jmod;
    int lf = (lane + 20) & 63;
    int lg = (lane + 40) & 63;
    int typ = lane / 20;
    float actB = (typ == 2) ? -2.f : -1.f;
    float actA = (typ == 2) ? 2.f : 1.f;
    float actC = (typ == 2) ? -1.f : 0.f;
    volatile int* pcnt = &pcntS[chain];
    volatile int* ccnt = &ccntS[chain];

    if (role == 0) {
      float4 wA[5], wB[5], iA[5], iB[5];
      GLOAD_ROW5(wA, Whh0 + rA * 20);
      GLOAD_ROW5(wB, Whh0 + rB * 20);
      GLOAD_ROW5(iA, Wih1 + rA * 20);
      GLOAD_ROW5(iB, Wih1 + rB * 20);
      GWAIT();
      float bA1c = bih1[rA] + bhh1[rA];
      float bB1c = bih1[rB] + bhh1[rB];
      CHUNKWAIT(0);                     // first 64 rows of both chains ready
      const float* prow = xw + ((size_t)b * 256 + (chain ? 255 : 0)) * 80;
      int pstep = chain ? -80 : 80;
      float pA0 = prow[rA], pB0 = prow[rB]; prow += pstep;
      float pA1 = prow[rA], pB1 = prow[rB]; prow += pstep;
      float pA2 = prow[rA], pB2 = prow[rB]; prow += pstep;
      float pA3 = prow[rA], pB3 = prow[rB]; prow += pstep;

      float sh1[20];
      float c1;
      {   // step 0: input = mu projection, h=c=0
        float preA = wsF[WS_XWMU + rA];
        float preB = wsF[WS_XWMU + rB];
        float aA = fmaf(actA, __builtin_amdgcn_rcpf(1.f + __expf(actB * preA)), actC);
        float aB = sigm(preB);
        float gv = __shfl(aA, lg);
        c1 = aA * gv;
        float h1j = aB * tanh_fast(c1);
        READ_H(sh1, h1j);
        float xpA, xpB;
        DOT20(xpA, iA, sh1, bA1c, 0.f);
        DOT20(xpB, iB, sh1, bB1c, 0.f);
        xpring[chain][0][lane] = xpA;
        xpring[chain][0][64 + lane] = xpB;
        LGKM0();
        *pcnt = 1;
        MEMFENCE();
      }
#pragma unroll 1
      for (int t = 1; t <= 253; t += 4) {
        if (((t - 1) & 15) == 0) {
          if (t == 49) CHUNKWAIT(1);    // middle f-chunk needed from row ~64
          while (*ccnt < t - 13) { }
          MEMFENCE();
        }
        PSTEP(pA0, pB0, t);
        PSTEP(pA1, pB1, t + 1);
        PSTEP(pA2, pB2, t + 2);
        PSTEP(pA3, pB3, t + 3);
        LGKM0();
        *pcnt = t + 4;
        MEMFENCE();
      }
    } else {
      float4 hA[5], hB[5];
      GLOAD_ROW5(hA, Whh1 + rA * 20);
      GLOAD_ROW5(hB, Whh1 + rB * 20);
      GWAIT();
      float sh2[20];
#pragma unroll
      for (int k = 0; k < 20; ++k) sh2[k] = 0.f;
      float c2 = 0.f;
      float h2j = 0.f;
#pragma unroll 1
      for (int t = 0; t <= 252; t += 4) {
        while (*pcnt < t + 4) { }
        MEMFENCE();
        int sl = t & 31;
        float xA0 = xpring[chain][sl][lane],     xB0 = xpring[chain][sl][64 + lane];
        float xA1 = xpring[chain][sl + 1][lane], xB1 = xpring[chain][sl + 1][64 + lane];
        float xA2 = xpring[chain][sl + 2][lane], xB2 = xpring[chain][sl + 2][64 + lane];
        float xA3 = xpring[chain][sl + 3][lane], xB3 = xpring[chain][sl + 3][64 + lane];
        CSTEP(xA0, xB0);
        CSTEP(xA1, xB1);
        CSTEP(xA2, xB2);
        CSTEP(xA3, xB3);
        *ccnt = t + 4;
        MEMFENCE();
      }
      {   // tail step t=256
        while (*pcnt < 257) { }
        MEMFENCE();
        float xA = xpring[chain][256 & 31][lane];
        float xB = xpring[chain][256 & 31][64 + lane];
        CSTEP(xA, xB);
        if (lane < 20) hb[chain][lane] = h2j;
      }
    }
  }

  __syncthreads();
  if (tid == 0) {
    float y = bv[0];
#pragma unroll
    for (int j = 0; j < 20; ++j) y = fmaf(Wv[j], hb[0][j], y);
#pragma unroll
    for (int j = 0; j < 20; ++j) y = fmaf(Wv[20 + j], hb[1][j], y);
    out[b] = y;
  }
}

extern "C" void kernel_launch(void* const* d_in, const int* in_sizes, int n_in,
                              void* d_out, int out_size, void* d_ws, size_t ws_size,
                              hipStream_t stream)
{
  const float* x    = (const float*)d_in[0];
  const float* W_N  = (const float*)d_in[1];
  const float* b_N  = (const float*)d_in[2];
  const float* W_up = (const float*)d_in[3];
  const float* b_up = (const float*)d_in[4];
  const float* mu   = (const float*)d_in[5];
  const float* Wih0 = (const float*)d_in[6];
  const float* Whh0 = (const float*)d_in[7];
  const float* bih0 = (const float*)d_in[8];
  const float* bhh0 = (const float*)d_in[9];
  const float* Wih1 = (const float*)d_in[10];
  const float* Whh1 = (const float*)d_in[11];
  const float* bih1 = (const float*)d_in[12];
  const float* bhh1 = (const float*)d_in[13];
  const float* Wv   = (const float*)d_in[14];
  const float* bvv  = (const float*)d_in[15];
  float* wsF = (float*)d_ws;
  float* xwp = wsF + WS_XW;
  float* outF = (float*)d_out;

  prep_cols_kernel<<<514, 256, 0, stream>>>(W_N, b_N, W_up, b_up,
                                            mu, Wih0, bih0, bhh0, wsF);
  xwlstm_kernel<<<B_, 512, 0, stream>>>(x, Wih0, wsF, Whh0, Wih1, Whh1,
                                        bih1, bhh1, Wv, bvv, xwp, outF);
}